// Round 11
// baseline (300.513 us; speedup 1.0000x reference)
//
#include <hip/hip_runtime.h>
#include <hip/hip_bf16.h>

#define L_SZ 1024
#define P_SZ 2048
#define HID 256
#define NH 8
#define HD 32
#define NRBF 50
#define CH 32
#define NCH 64

typedef unsigned int uint32;
typedef _Float16 half2_t __attribute__((ext_vector_type(2)));
typedef __fp16 fp16x2_t __attribute__((ext_vector_type(2)));

__constant__ float kINV_SCALE = 0.17677669529663687f; // 1/sqrt(32)

static __device__ __forceinline__ unsigned short f2h(float f) {
    union { _Float16 h; unsigned short u; } x; x.h = (_Float16)f; return x.u;
}
static __device__ __forceinline__ float h2f(unsigned short u) {
    union { unsigned short u; _Float16 h; } x; x.u = u; return (float)x.h;
}
static __device__ __forceinline__ half2_t u2h2(uint32 u) {
    union { uint32 u; half2_t h; } x; x.u = u; return x.h;
}
static __device__ __forceinline__ half2_t pk2h(float a, float b) {
    union { fp16x2_t p; half2_t h; } x; x.p = __builtin_amdgcn_cvt_pkrtz(a, b); return x.h;
}

// async global->LDS, 16B per lane. LDS dest = wave-uniform base + lane*16.
static __device__ __forceinline__ void g2l16(const void* g, void* l) {
    __builtin_amdgcn_global_load_lds(
        (__attribute__((address_space(1))) void*)(void*)g,
        (__attribute__((address_space(3))) void*)l, 16, 0, 0);
}
static __device__ __forceinline__ void g2l4(const void* g, void* l) {
    __builtin_amdgcn_global_load_lds(
        (__attribute__((address_space(1))) void*)(void*)g,
        (__attribute__((address_space(3))) void*)l, 4, 0, 0);
}

#define WAITV0 asm volatile("s_waitcnt vmcnt(0)" ::: "memory")
#define WAITV1 asm volatile("s_waitcnt vmcnt(1)" ::: "memory")
#define CFENCE asm volatile("" ::: "memory")

// ---------------------------------------------------------------------------
// Kernel 1: Q = lig@Wq+bq (f32), K = prot@Wk+bk (f16), V = prot@Wv+bv (f16)
// ---------------------------------------------------------------------------
__global__ __launch_bounds__(64) void k_proj(
    const float* __restrict__ lig, const float* __restrict__ prot,
    const float* __restrict__ Wq, const float* __restrict__ bq,
    const float* __restrict__ Wk, const float* __restrict__ bk,
    const float* __restrict__ Wv, const float* __restrict__ bv,
    float* __restrict__ Qf, unsigned short* __restrict__ Kb,
    unsigned short* __restrict__ Vb)
{
    __shared__ float As[8 * HID];
    const int t = threadIdx.x;
    const int r0 = blockIdx.x * 8;

    const float* src; const float* W; const float* bias; int mode; int row0;
    if (r0 < L_SZ)            { src = lig  + (size_t)r0 * HID;               W = Wq; bias = bq; mode = 0; row0 = r0; }
    else if (r0 < L_SZ + P_SZ){ src = prot + (size_t)(r0 - L_SZ) * HID;      W = Wk; bias = bk; mode = 1; row0 = r0 - L_SZ; }
    else                      { src = prot + (size_t)(r0 - L_SZ - P_SZ)*HID; W = Wv; bias = bv; mode = 2; row0 = r0 - L_SZ - P_SZ; }

    float4* A4 = (float4*)As;
    const float4* S4 = (const float4*)src;
    #pragma unroll
    for (int j = 0; j < 8; ++j) A4[t + j * 64] = S4[t + j * 64];
    __syncthreads();

    float acc[8][4];
    #pragma unroll
    for (int r = 0; r < 8; ++r)
        #pragma unroll
        for (int c = 0; c < 4; ++c) acc[r][c] = 0.f;

    for (int k4 = 0; k4 < 64; ++k4) {
        float4 av[8];
        #pragma unroll
        for (int r = 0; r < 8; ++r) av[r] = A4[r * 64 + k4];
        #pragma unroll
        for (int kk = 0; kk < 4; ++kk) {
            const float* wr = W + (size_t)(k4 * 4 + kk) * HID + t;
            #pragma unroll
            for (int c = 0; c < 4; ++c) {
                float wv = wr[c * 64];
                #pragma unroll
                for (int r = 0; r < 8; ++r)
                    acc[r][c] += ((const float*)&av[r])[kk] * wv;
            }
        }
    }

    #pragma unroll
    for (int c = 0; c < 4; ++c) {
        const int col = t + c * 64;
        const float bb = bias[col];
        #pragma unroll
        for (int r = 0; r < 8; ++r) {
            float v = acc[r][c] + bb;
            size_t idx = (size_t)(row0 + r) * HID + col;
            if (mode == 0)      Qf[idx] = v;
            else if (mode == 1) Kb[idx] = f2h(v);
            else                Vb[idx] = f2h(v);
        }
    }
}

// ---------------------------------------------------------------------------
// Kernel 2: 2 ligand rows per 512-thread block; single fused flash loop.
// Wave w: lig = w>>2 (uniform), h = 2*(w&3) + (lane>>5), r = lane&31 —
// preserves R10's zero-conflict LDS read patterns while K/V staging is
// amortized over 2 ligand rows (8 waves co-stage each 16KB chunk).
// LDS: K dbuf 2x16384 @0 | V dbuf 2x16384 @32768 |
//      rbf dbuf 2 x (2 lig x 6400) @65536 | red[32] @91136. Total 91264 B.
// 1 block/CU (8 waves). otr (64KB) overlays K+V dbufs post-loop.
// ---------------------------------------------------------------------------
__global__ __launch_bounds__(512, 2) void k_attn(
    const float* __restrict__ rbf, const float* __restrict__ Qf,
    const unsigned short* __restrict__ Kb, const unsigned short* __restrict__ Vb,
    const float* __restrict__ Wrbf, const float* __restrict__ brbf,
    float* __restrict__ attn_out, float* __restrict__ att_ws)
{
    __shared__ __align__(16) char sm[91264];
    char* vBB  = sm + 32768;
    char* rbfB = sm + 65536;
    float* red = (float*)(sm + 91136);     // [2 lig][8 h][m, 1/sum]

    const int t = threadIdx.x;
    const int lane = t & 63;
    const int wv = t >> 6;                 // wave 0..7
    const int r = lane & 31;               // protein row within chunk
    const int lig = wv >> 2;               // wave-uniform ligand select
    const int h = ((wv & 3) << 1) + (lane >> 5);   // head 0..7
    const int l0 = blockIdx.x * 2;

    char* aoB = (char*)attn_out + (size_t)(l0 + lig) * (P_SZ * NH * 4);

    // stage one 32-row K or V chunk (16 KB) with 8 waves, XOR-swizzled via
    // pre-swizzled global source (LDS dest linear). 2 loads per wave.
    auto stageKV = [&](const unsigned short* src, int c, char* dst) {
        const char* gb = (const char*)src + (size_t)c * (CH * 512);
        #pragma unroll
        for (int k = 0; k < 2; ++k) {
            int s = wv * 2 + k;               // 1KB slab 0..15
            int row = s * 2 + (lane >> 5);
            int off = ((lane & 31) ^ (row & 31)) << 4;
            g2l16(gb + row * 512 + off, dst + s * 1024);
        }
    };
    // stage one 32-row rbf chunk (6400 B) for EACH lig row: waves pair up,
    // lw = wv&1 selects the lig, w4 = wv>>1 replicates the proven 4-wave plan.
    auto stageRBF2 = [&](int c, char* dstBase) {
        const int lw = wv & 1, w4 = wv >> 1;
        const char* gb = (const char*)rbf + (size_t)(l0 + lw) * 409600 + (size_t)c * 6400;
        char* dst = dstBase + lw * 6400;
        g2l16(gb + w4 * 1024 + (lane << 4), dst + w4 * 1024);
        if (w4 == 0)      g2l16(gb + 4096 + (lane << 4), dst + 4096);
        else if (w4 == 1) g2l16(gb + 5120 + (lane << 4), dst + 5120);
        else if (w4 == 2) g2l4 (gb + 6144 + (lane << 2), dst + 6144);
    };

    // ---- per-thread preloads: Wrbf column h (25 half2), Q head h (16 half2)
    half2_t wrb[25];
    #pragma unroll
    for (int j = 0; j < 25; ++j)
        wrb[j] = pk2h(Wrbf[(2 * j) * NH + h], Wrbf[(2 * j + 1) * NH + h]);
    const float bh = brbf[h];

    half2_t qp[16];
    {
        const float* qq = Qf + (size_t)(l0 + lig) * HID + h * HD;
        #pragma unroll
        for (int n = 0; n < 16; ++n)
            qp[n] = pk2h(qq[2 * n], qq[2 * n + 1]);
    }

    // ================= Single fused flash loop ==============================
    stageKV(Kb, 0, sm);
    stageKV(Vb, 0, vBB);
    stageRBF2(0, rbfB);

    float mx = -3.0e38f, sme = 0.f;
    float O[32];
    #pragma unroll
    for (int d = 0; d < 32; ++d) O[d] = 0.f;

    for (int c = 0; c < NCH; ++c) {
        if (c == 0) { WAITV0; } else { WAITV1; }   // leave raw store in flight
        __builtin_amdgcn_s_barrier();
        CFENCE;
        const int cb = c & 1;
        char* kb = sm + cb * 16384;
        char* vb = vBB + cb * 16384;
        char* rb = rbfB + cb * 12800 + lig * 6400;
        if (c + 1 < NCH) {                   // prefetch with a full iter of slack
            stageKV(Kb, c + 1, sm + (cb ^ 1) * 16384);
            stageKV(Vb, c + 1, vBB + (cb ^ 1) * 16384);
            stageRBF2(c + 1, rbfB + (cb ^ 1) * 12800);
        }
        // bias = brbf[h] + rbf[l0+lig, p, :] . Wrbf[:, h]   (dual chains)
        float b0 = bh, b1 = 0.f;
        const char* rrow = rb + r * 200;
        #pragma unroll
        for (int j = 0; j < 12; ++j) {
            float2 v0 = *(const float2*)(rrow + (2 * j) * 8);
            float2 v1 = *(const float2*)(rrow + (2 * j + 1) * 8);
            b0 = __builtin_amdgcn_fdot2(pk2h(v0.x, v0.y), wrb[2 * j], b0, false);
            b1 = __builtin_amdgcn_fdot2(pk2h(v1.x, v1.y), wrb[2 * j + 1], b1, false);
        }
        {
            float2 v = *(const float2*)(rrow + 24 * 8);
            b0 = __builtin_amdgcn_fdot2(pk2h(v.x, v.y), wrb[24], b0, false);
        }
        // qk = Q[l0+lig,h,:] . K[p,h,:]   (dual chains)
        float qk0 = 0.f, qk1 = 0.f;
        const char* krow = kb + r * 512;
        #pragma unroll
        for (int jw = 0; jw < 2; ++jw) {
            int offA = (h * 64 + jw * 16) ^ (r << 4);
            int offB = (h * 64 + (jw + 2) * 16) ^ (r << 4);
            uint4 ka = *(const uint4*)(krow + offA);
            uint4 kbv = *(const uint4*)(krow + offB);
            qk0 = __builtin_amdgcn_fdot2(u2h2(ka.x),  qp[jw * 4 + 0], qk0, false);
            qk1 = __builtin_amdgcn_fdot2(u2h2(kbv.x), qp[(jw + 2) * 4 + 0], qk1, false);
            qk0 = __builtin_amdgcn_fdot2(u2h2(ka.y),  qp[jw * 4 + 1], qk0, false);
            qk1 = __builtin_amdgcn_fdot2(u2h2(kbv.y), qp[(jw + 2) * 4 + 1], qk1, false);
            qk0 = __builtin_amdgcn_fdot2(u2h2(ka.z),  qp[jw * 4 + 2], qk0, false);
            qk1 = __builtin_amdgcn_fdot2(u2h2(kbv.z), qp[(jw + 2) * 4 + 2], qk1, false);
            qk0 = __builtin_amdgcn_fdot2(u2h2(ka.w),  qp[jw * 4 + 3], qk0, false);
            qk1 = __builtin_amdgcn_fdot2(u2h2(kbv.w), qp[(jw + 2) * 4 + 3], qk1, false);
        }
        float lg = (qk0 + qk1) * kINV_SCALE + (b0 + b1);

        // online softmax with defer-max (THR=8): P bounded by e^8, f32-safe
        if (lg > mx + 8.0f) {
            float e = __expf(mx - lg);           // 0 on first trigger
            sme *= e;
            #pragma unroll
            for (int d = 0; d < 32; ++d) O[d] *= e;
            mx = lg;
        }
        float w = __expf(lg - mx);
        sme += w;

        // flash-PV: O += w * V[p, h*32 : h*32+32]
        const char* vrow = vb + r * 512;
        #pragma unroll
        for (int q = 0; q < 4; ++q) {
            int off = (h * 64 + q * 16) ^ (r << 4);
            uint4 vvv = *(const uint4*)(vrow + off);
            half2_t x0 = u2h2(vvv.x), x1 = u2h2(vvv.y), x2 = u2h2(vvv.z), x3 = u2h2(vvv.w);
            O[q * 8 + 0] += w * (float)x0.x; O[q * 8 + 1] += w * (float)x0.y;
            O[q * 8 + 2] += w * (float)x1.x; O[q * 8 + 3] += w * (float)x1.y;
            O[q * 8 + 4] += w * (float)x2.x; O[q * 8 + 5] += w * (float)x2.y;
            O[q * 8 + 6] += w * (float)x3.x; O[q * 8 + 7] += w * (float)x3.y;
        }

        // raw f16 logit -> low half of (l0+lig)'s attn_out region
        *(unsigned short*)(aoB + (c * CH + r) * 16 + h * 2) = f2h(lg);
    }
    WAITV0;                                      // drain raw logit stores

    // ---- merge (m,s) across the 32 lanes owning (lig, h) ----
    float mg = mx;
    #pragma unroll
    for (int msk = 1; msk <= 16; msk <<= 1) mg = fmaxf(mg, __shfl_xor(mg, msk));
    float e = __expf(mx - mg);
    sme *= e;
    #pragma unroll
    for (int msk = 1; msk <= 16; msk <<= 1) sme += __shfl_xor(sme, msk);
    float inv = 1.0f / sme;
    if (r == 0) { red[(lig * 8 + h) * 2] = mg; red[(lig * 8 + h) * 2 + 1] = inv; }
    const float scl = e * inv;                   // per-lane O scale

    __syncthreads();                             // K/V dbufs free; red published

    // ---- O transpose-reduce via LDS (rotate-swizzled, conflict-free) ----
    {
        float* otr = (float*)sm;                 // 64 KB over K+V dbufs
        const int ro = ((lig * 8 + h) * 32 + r) * 32;
        #pragma unroll
        for (int d = 0; d < 32; ++d)
            otr[ro + ((d + r) & 31)] = O[d] * scl;
        __syncthreads();
        const int lg2 = t >> 8, hh = (t >> 5) & 7, dd = t & 31;
        float a = 0.f;
        #pragma unroll
        for (int rr = 0; rr < 32; ++rr)
            a += otr[((lg2 * 8 + hh) * 32 + rr) * 32 + ((dd + rr) & 31)];
        att_ws[(size_t)(l0 + lg2) * HID + hh * HD + dd] = a;
    }

    // ---- in-place finalize raw f16 -> f32 weights (descending, proven) ----
    {
        const int hA = 2 * (t & 3);
        for (int lgf = 0; lgf < 2; ++lgf) {
            char* rg = (char*)attn_out + (size_t)(l0 + lgf) * (P_SZ * NH * 4);
            const float mA = red[(lgf * 8 + hA) * 2],     iA = red[(lgf * 8 + hA) * 2 + 1];
            const float mB = red[(lgf * 8 + hA + 1) * 2], iB = red[(lgf * 8 + hA + 1) * 2 + 1];
            for (int n = 15; n >= 0; --n) {
                int j = t + n * 512;
                uint32 a = *(const uint32*)(rg + 4 * (size_t)j);
                float w0 = __expf(h2f((unsigned short)(a & 0xffffu)) - mA) * iA;
                float w1 = __expf(h2f((unsigned short)(a >> 16))     - mB) * iB;
                __syncthreads();
                *(float2*)(rg + 8 * (size_t)j) = make_float2(w0, w1);
            }
        }
    }
}

// ---------------------------------------------------------------------------
// Kernel 3: y = lig + attended@Wo + bo; LayerNorm
// ---------------------------------------------------------------------------
__global__ __launch_bounds__(256) void k_out(
    const float* __restrict__ att, const float* __restrict__ lig,
    const float* __restrict__ Wo, const float* __restrict__ bo,
    const float* __restrict__ gamma, const float* __restrict__ beta,
    float* __restrict__ out)
{
    __shared__ float a[HID];
    __shared__ float red[8];
    const int l = blockIdx.x, t = threadIdx.x;
    if (t < 64) ((float4*)a)[t] = ((const float4*)(att + (size_t)l * HID))[t];
    __syncthreads();

    float acc = bo[t];
    for (int k4 = 0; k4 < 64; ++k4) {
        float4 av = ((float4*)a)[k4];
        const float* wr = Wo + (size_t)(k4 * 4) * HID + t;
        acc += av.x * wr[0];
        acc += av.y * wr[HID];
        acc += av.z * wr[2 * HID];
        acc += av.w * wr[3 * HID];
    }
    float y = lig[(size_t)l * HID + t] + acc;

    float s = y, sq = y * y;
    #pragma unroll
    for (int msk = 1; msk < 64; msk <<= 1) {
        s  += __shfl_xor(s, msk);
        sq += __shfl_xor(sq, msk);
    }
    const int lane = t & 63, wvi = t >> 6;
    if (lane == 0) { red[wvi * 2] = s; red[wvi * 2 + 1] = sq; }
    __syncthreads();
    float ts = red[0] + red[2] + red[4] + red[6];
    float tq = red[1] + red[3] + red[5] + red[7];
    float mu = ts * (1.0f / HID);
    float var = tq * (1.0f / HID) - mu * mu;
    out[(size_t)l * HID + t] = (y - mu) * rsqrtf(var + 1e-5f) * gamma[t] + beta[t];
}

// ---------------------------------------------------------------------------
extern "C" void kernel_launch(void* const* d_in, const int* in_sizes, int n_in,
                              void* d_out, int out_size, void* d_ws, size_t ws_size,
                              hipStream_t stream)
{
    (void)in_sizes; (void)n_in; (void)out_size; (void)ws_size;

    const float* lig   = (const float*)d_in[0];
    const float* prot  = (const float*)d_in[1];
    const float* rbf   = (const float*)d_in[2];
    const float* Wq    = (const float*)d_in[5];
    const float* bq    = (const float*)d_in[6];
    const float* Wk    = (const float*)d_in[7];
    const float* bk    = (const float*)d_in[8];
    const float* Wv    = (const float*)d_in[9];
    const float* bv    = (const float*)d_in[10];
    const float* Wrbf  = (const float*)d_in[11];
    const float* brbf  = (const float*)d_in[12];
    const float* Wo    = (const float*)d_in[13];
    const float* bo    = (const float*)d_in[14];
    const float* gamma = (const float*)d_in[15];
    const float* beta  = (const float*)d_in[16];

    float* out0 = (float*)d_out;                          // [1024,256]
    float* attn = (float*)d_out + (size_t)L_SZ * HID;     // [1024,2048,8]

    char* ws = (char*)d_ws;
    float*          Qf     = (float*)ws;                          // 1 MB
    unsigned short* Kb     = (unsigned short*)(ws + (1u << 20));  // 1 MB
    unsigned short* Vb     = (unsigned short*)(ws + (2u << 20));  // 1 MB
    float*          att_ws = (float*)(ws + (3u << 20));           // 1 MB

    hipLaunchKernelGGL(k_proj, dim3((L_SZ + 2 * P_SZ) / 8), dim3(64), 0, stream,
                       lig, prot, Wq, bq, Wk, bk, Wv, bv, Qf, Kb, Vb);
    hipLaunchKernelGGL(k_attn, dim3(L_SZ / 2), dim3(512), 0, stream,
                       rbf, Qf, Kb, Vb, Wrbf, brbf, attn, att_ws);
    hipLaunchKernelGGL(k_out, dim3(L_SZ), dim3(256), 0, stream,
                       att_ws, lig, Wo, bo, gamma, beta, out0);
}